// Round 1
// baseline (829.651 us; speedup 1.0000x reference)
//
#include <hip/hip_runtime.h>
#include <cfloat>
#include <cmath>
#include <cstdint>

#define N_NODES 128
#define F_IN    256
#define HDIM    512
#define NEDGE   524288

// ---------------------------------------------------------------------------
// K0: adjacency bitmask  mask[d] = bitset over s of "edge (s -> d) exists"
// 128 nodes -> 4 u32 words per d. LDS-aggregated, then global atomicOr.
// ---------------------------------------------------------------------------
__global__ __launch_bounds__(256) void build_mask_kernel(
    const int* __restrict__ ei, unsigned int* __restrict__ mask) {
  __shared__ unsigned int lm[N_NODES * 4];
  const int t = threadIdx.x;
  for (int i = t; i < N_NODES * 4; i += 256) lm[i] = 0u;
  __syncthreads();
  const int base = blockIdx.x * 2048;
#pragma unroll
  for (int r = 0; r < 8; ++r) {
    const int e = base + r * 256 + t;
    const int s = ei[e];          // src  (x_j)
    const int d = ei[NEDGE + e];  // dst  (x_i, segment target)
    atomicOr(&lm[d * 4 + (s >> 5)], 1u << (s & 31));
  }
  __syncthreads();
  for (int i = t; i < N_NODES * 4; i += 256) {
    const unsigned int v = lm[i];
    if (v) atomicOr(&mask[i], v);
  }
}

// ---------------------------------------------------------------------------
// K1/K3: U[d,h] = A[d]@(Wtop - Wbot)[.,h] + b[h],  V[d,h] = A[d]@Wbot[.,h]
// A: [128, KK], W: [2*KK, 512].  8 d-rows per block, 256 h-cols per block.
// ---------------------------------------------------------------------------
template <int KK>
__global__ __launch_bounds__(256) void uv_gemm_kernel(
    const float* __restrict__ A, const float* __restrict__ W,
    const float* __restrict__ bias, float* __restrict__ U,
    float* __restrict__ V) {
  __shared__ float xs[8][KK];
  const int t = threadIdx.x;
  const int h = blockIdx.x * 256 + t;
  const int d0 = blockIdx.y * 8;
  for (int i = t; i < 8 * KK; i += 256) {
    const int dd = i / KK, k = i % KK;
    xs[dd][k] = A[(d0 + dd) * KK + k];
  }
  __syncthreads();
  float accT[8], accB[8];
#pragma unroll
  for (int dd = 0; dd < 8; ++dd) { accT[dd] = 0.f; accB[dd] = 0.f; }
  for (int k = 0; k < KK; ++k) {
    const float wt = W[k * HDIM + h];
    const float wb = W[(KK + k) * HDIM + h];
#pragma unroll
    for (int dd = 0; dd < 8; ++dd) {
      const float xa = xs[dd][k];
      accT[dd] = fmaf(xa, wt, accT[dd]);
      accB[dd] = fmaf(xa, wb, accB[dd]);
    }
  }
  const float bb = bias[h];
#pragma unroll
  for (int dd = 0; dd < 8; ++dd) {
    U[(d0 + dd) * HDIM + h] = accT[dd] - accB[dd] + bb;
    V[(d0 + dd) * HDIM + h] = accB[dd];
  }
}

// ---------------------------------------------------------------------------
// K2/K4: per-d pair GEMM + fused masked max + bias + relu.
//   A[s,k] = relu(U[d,k] + V[s,k])   (built on the fly, never materialized)
//   M[s,c] = A @ W2[:, c0..c0+128]
//   out[d,c] = max(0, b2[c] + max_{s in adj(d)} M[s,c])
// Grid: (4 col-tiles of 128, 128 d).  Block: 256 threads, 8x8 microtile.
// ---------------------------------------------------------------------------
__global__ __launch_bounds__(256) void pair_gemm_max_kernel(
    const float* __restrict__ U, const float* __restrict__ V,
    const float* __restrict__ W2, const float* __restrict__ b2,
    const unsigned int* __restrict__ mask, float* __restrict__ out) {
  __shared__ float As[16][128];
  __shared__ float Bs[16][128];
  const int t = threadIdx.x;
  const int tx = t & 15, ty = t >> 4;
  const int d = blockIdx.y;
  const int c0 = blockIdx.x * 128;

  float acc[8][8];
#pragma unroll
  for (int i = 0; i < 8; ++i)
#pragma unroll
    for (int j = 0; j < 8; ++j) acc[i][j] = 0.f;

  for (int kb = 0; kb < HDIM / 16; ++kb) {
    __syncthreads();
    // Stage A tile: relu(U[d, k] + V[s, k]) for s in [0,128), k in 16-chunk.
#pragma unroll
    for (int r = 0; r < 2; ++r) {
      const int q = t + r * 256;
      const int s = q >> 2;
      const int k4 = (q & 3) * 4;
      const float4 v4 = *reinterpret_cast<const float4*>(&V[s * HDIM + kb * 16 + k4]);
      const float4 u4 = *reinterpret_cast<const float4*>(&U[d * HDIM + kb * 16 + k4]);
      As[k4 + 0][s] = fmaxf(u4.x + v4.x, 0.f);
      As[k4 + 1][s] = fmaxf(u4.y + v4.y, 0.f);
      As[k4 + 2][s] = fmaxf(u4.z + v4.z, 0.f);
      As[k4 + 3][s] = fmaxf(u4.w + v4.w, 0.f);
    }
    // Stage B tile: W2[k, c0..c0+128]
#pragma unroll
    for (int r = 0; r < 2; ++r) {
      const int q = t + r * 256;
      const int k = q >> 5;
      const int c4 = (q & 31) * 4;
      *reinterpret_cast<float4*>(&Bs[k][c4]) =
          *reinterpret_cast<const float4*>(&W2[(kb * 16 + k) * HDIM + c0 + c4]);
    }
    __syncthreads();
#pragma unroll
    for (int k = 0; k < 16; ++k) {
      const float4 a0 = *reinterpret_cast<const float4*>(&As[k][ty * 8]);
      const float4 a1 = *reinterpret_cast<const float4*>(&As[k][ty * 8 + 4]);
      const float4 b0 = *reinterpret_cast<const float4*>(&Bs[k][tx * 8]);
      const float4 b1 = *reinterpret_cast<const float4*>(&Bs[k][tx * 8 + 4]);
      const float av[8] = {a0.x, a0.y, a0.z, a0.w, a1.x, a1.y, a1.z, a1.w};
      const float bv[8] = {b0.x, b0.y, b0.z, b0.w, b1.x, b1.y, b1.z, b1.w};
#pragma unroll
      for (int i = 0; i < 8; ++i)
#pragma unroll
        for (int j = 0; j < 8; ++j) acc[i][j] = fmaf(av[i], bv[j], acc[i][j]);
    }
  }
  __syncthreads();

  // Masked max over the 8 s-rows this thread owns (rows ty*8..ty*8+7 all live
  // in mask word (ty>>2), bits (ty&3)*8 + i).
  const unsigned int w = mask[d * 4 + (ty >> 2)];
  float cm[8];
#pragma unroll
  for (int j = 0; j < 8; ++j) cm[j] = -FLT_MAX;
#pragma unroll
  for (int i = 0; i < 8; ++i) {
    if ((w >> ((ty & 3) * 8 + i)) & 1u) {
#pragma unroll
      for (int j = 0; j < 8; ++j) cm[j] = fmaxf(cm[j], acc[i][j]);
    }
  }
  // Cross-ty reduction through LDS (reuse As: 16x128 floats).
  float(*red)[128] = As;
#pragma unroll
  for (int j = 0; j < 8; ++j) red[ty][tx * 8 + j] = cm[j];
  __syncthreads();
  if (t < 128) {
    float m = -FLT_MAX;
#pragma unroll
    for (int r2 = 0; r2 < 16; ++r2) m = fmaxf(m, red[r2][t]);
    const int gc = c0 + t;
    // empty adjacency -> m = -FLT_MAX -> m + b2 << 0 -> result 0 (matches ref)
    out[d * HDIM + gc] = fmaxf(m + b2[gc], 0.f);
  }
}

// ---------------------------------------------------------------------------
// K5: z0[j] += sum_i v[i] * lin_W[i, j]  (split-K over 512 blocks of 128 rows)
// ---------------------------------------------------------------------------
__global__ __launch_bounds__(256) void head_gemv_kernel(
    const float* __restrict__ v, const float* __restrict__ W,
    float* __restrict__ z0) {
  __shared__ float vs[128];
  const int t = threadIdx.x;
  const int bi = blockIdx.x;
  if (t < 128) vs[t] = v[bi * 128 + t];
  __syncthreads();
  const float* Wp = W + (size_t)bi * 128 * 512;
  float a0 = 0.f, a1 = 0.f;
#pragma unroll 4
  for (int i = 0; i < 128; ++i) {
    const float x = vs[i];
    a0 = fmaf(x, Wp[i * 512 + t], a0);
    a1 = fmaf(x, Wp[i * 512 + 256 + t], a1);
  }
  atomicAdd(&z0[t], a0);
  atomicAdd(&z0[t + 256], a1);
}

// ---------------------------------------------------------------------------
// K6: z1 = relu(relu(z0+lin_b) @ lin1_W + lin1_b); z2 = relu(z1 @ out_W + out_b)
//     out = softmax(z2).  Single block, 256 threads.
// ---------------------------------------------------------------------------
__global__ __launch_bounds__(256) void final_head_kernel(
    const float* __restrict__ z0pre, const float* __restrict__ lin_b,
    const float* __restrict__ lin1W, const float* __restrict__ lin1b,
    const float* __restrict__ outW, const float* __restrict__ outb,
    float* __restrict__ out) {
  __shared__ float z0s[512];
  __shared__ float z1s[256];
  __shared__ float z2s[128];
  __shared__ float r[128];
  const int t = threadIdx.x;
  z0s[t] = fmaxf(z0pre[t] + lin_b[t], 0.f);
  z0s[t + 256] = fmaxf(z0pre[t + 256] + lin_b[t + 256], 0.f);
  __syncthreads();
  float acc = lin1b[t];
  for (int i = 0; i < 512; ++i) acc = fmaf(z0s[i], lin1W[i * 256 + t], acc);
  z1s[t] = fmaxf(acc, 0.f);
  __syncthreads();
  if (t < 128) {
    float a2 = outb[t];
    for (int i = 0; i < 256; ++i) a2 = fmaf(z1s[i], outW[i * 128 + t], a2);
    z2s[t] = fmaxf(a2, 0.f);
    r[t] = z2s[t];
  }
  __syncthreads();
  for (int off = 64; off > 0; off >>= 1) {
    if (t < off) r[t] = fmaxf(r[t], r[t + off]);
    __syncthreads();
  }
  const float mx = r[0];
  __syncthreads();
  if (t < 128) {
    const float e = expf(z2s[t] - mx);
    z2s[t] = e;
    r[t] = e;
  }
  __syncthreads();
  for (int off = 64; off > 0; off >>= 1) {
    if (t < off) r[t] += r[t + off];
    __syncthreads();
  }
  const float sm = r[0];
  if (t < 128) out[t] = z2s[t] / sm;
}

// ---------------------------------------------------------------------------
extern "C" void kernel_launch(void* const* d_in, const int* in_sizes, int n_in,
                              void* d_out, int out_size, void* d_ws,
                              size_t ws_size, hipStream_t stream) {
  const float* x      = (const float*)d_in[0];
  const int*   ei     = (const int*)d_in[1];
  const float* c1_W1  = (const float*)d_in[2];
  const float* c1_b1  = (const float*)d_in[3];
  const float* c1_W2  = (const float*)d_in[4];
  const float* c1_b2  = (const float*)d_in[5];
  const float* c2_W1  = (const float*)d_in[6];
  const float* c2_b1  = (const float*)d_in[7];
  const float* c2_W2  = (const float*)d_in[8];
  const float* c2_b2  = (const float*)d_in[9];
  const float* lin_W  = (const float*)d_in[10];
  const float* lin_b  = (const float*)d_in[11];
  const float* lin1_W = (const float*)d_in[12];
  const float* lin1_b = (const float*)d_in[13];
  const float* out_W  = (const float*)d_in[14];
  const float* out_b  = (const float*)d_in[15];
  float* out = (float*)d_out;

  char* wsb = (char*)d_ws;
  unsigned int* mask = (unsigned int*)wsb;       // 512 u32 = 2048 B
  float* U1 = (float*)(wsb + 2048);              // 128x512 each below
  float* V1 = U1 + 65536;
  float* h1 = V1 + 65536;
  float* U2 = h1 + 65536;
  float* V2 = U2 + 65536;
  float* h2 = V2 + 65536;
  float* z0 = h2 + 65536;                        // 512 floats

  hipMemsetAsync(mask, 0, 2048, stream);
  hipMemsetAsync(z0, 0, 512 * sizeof(float), stream);

  build_mask_kernel<<<256, 256, 0, stream>>>(ei, mask);
  uv_gemm_kernel<256><<<dim3(2, 16), 256, 0, stream>>>(x, c1_W1, c1_b1, U1, V1);
  pair_gemm_max_kernel<<<dim3(4, 128), 256, 0, stream>>>(U1, V1, c1_W2, c1_b2, mask, h1);
  uv_gemm_kernel<512><<<dim3(2, 16), 256, 0, stream>>>(h1, c2_W1, c2_b1, U2, V2);
  pair_gemm_max_kernel<<<dim3(4, 128), 256, 0, stream>>>(U2, V2, c2_W2, c2_b2, mask, h2);
  head_gemv_kernel<<<512, 256, 0, stream>>>(h2, lin_W, z0);
  final_head_kernel<<<1, 256, 0, stream>>>(z0, lin_b, lin1_W, lin1_b, out_W,
                                           out_b, out);
}

// Round 2
// 570.447 us; speedup vs baseline: 1.4544x; 1.4544x over previous
//
#include <hip/hip_runtime.h>
#include <cfloat>
#include <cmath>
#include <cstdint>

#define N_NODES 128
#define F_IN    256
#define HDIM    512
#define NEDGE   524288

// ---------------------------------------------------------------------------
// K0: adjacency bitmask  mask[d] = bitset over s of "edge (s -> d) exists"
// ---------------------------------------------------------------------------
__global__ __launch_bounds__(256) void build_mask_kernel(
    const int* __restrict__ ei, unsigned int* __restrict__ mask) {
  __shared__ unsigned int lm[N_NODES * 4];
  const int t = threadIdx.x;
  for (int i = t; i < N_NODES * 4; i += 256) lm[i] = 0u;
  __syncthreads();
  const int base = blockIdx.x * 2048;
#pragma unroll
  for (int r = 0; r < 8; ++r) {
    const int e = base + r * 256 + t;
    const int s = ei[e];          // src  (x_j)
    const int d = ei[NEDGE + e];  // dst  (x_i, segment target)
    atomicOr(&lm[d * 4 + (s >> 5)], 1u << (s & 31));
  }
  __syncthreads();
  for (int i = t; i < N_NODES * 4; i += 256) {
    const unsigned int v = lm[i];
    if (v) atomicOr(&mask[i], v);
  }
}

// ---------------------------------------------------------------------------
// K1/K3 v2: U[d,h] = A[d]@(Wtop - Wbot)[.,h] + b[h],  V[d,h] = A[d]@Wbot[.,h]
// LDS-tiled, split-K (S slices, atomicAdd into U/V which are pre-zeroed).
// Block: 128 d x 64 h, K-slice KK/S, chunks of BK=32.
// Grid: (8 h-tiles, S).  256 threads, microtile 8d x 4h (64 fp32 accs).
// ---------------------------------------------------------------------------
template <int KK, int S>
__global__ __launch_bounds__(256) void uv_gemm2_kernel(
    const float* __restrict__ A, const float* __restrict__ W,
    const float* __restrict__ bias, float* __restrict__ U,
    float* __restrict__ V) {
  constexpr int KS = KK / S;   // k per block
  constexpr int BK = 32;       // k per chunk
  __shared__ float As[128][BK + 1];
  __shared__ float Wd[BK][64];  // Wtop - Wbot
  __shared__ float Wb[BK][64];  // Wbot
  const int t = threadIdx.x;
  const int tx = t & 15;        // 4 h-cols each
  const int ty = t >> 4;        // 8 d-rows each
  const int h0 = blockIdx.x * 64;
  const int ks0 = blockIdx.y * KS;

  float accU[8][4], accV[8][4];
#pragma unroll
  for (int i = 0; i < 8; ++i)
#pragma unroll
    for (int j = 0; j < 4; ++j) { accU[i][j] = 0.f; accV[i][j] = 0.f; }

  for (int ch = 0; ch < KS / BK; ++ch) {
    const int k0 = ks0 + ch * BK;
    __syncthreads();
    // Stage A[128][32] (1024 float4 slots, 4 per thread)
#pragma unroll
    for (int ii = 0; ii < 4; ++ii) {
      const int slot = t + ii * 256;
      const int d = slot >> 3, kw = slot & 7;
      const float4 a4 = *reinterpret_cast<const float4*>(&A[d * KK + k0 + kw * 4]);
      As[d][kw * 4 + 0] = a4.x;
      As[d][kw * 4 + 1] = a4.y;
      As[d][kw * 4 + 2] = a4.z;
      As[d][kw * 4 + 3] = a4.w;
    }
    // Stage Wtop/Wbot chunk [32][64] each (512 float4 slots each, 2/thread)
#pragma unroll
    for (int ii = 0; ii < 2; ++ii) {
      const int slot = t + ii * 256;
      const int k = slot >> 4, h4 = (slot & 15) * 4;
      const float4 wt = *reinterpret_cast<const float4*>(
          &W[(size_t)(k0 + k) * HDIM + h0 + h4]);
      const float4 wb = *reinterpret_cast<const float4*>(
          &W[(size_t)(KK + k0 + k) * HDIM + h0 + h4]);
      *reinterpret_cast<float4*>(&Wb[k][h4]) = wb;
      float4 wd;
      wd.x = wt.x - wb.x; wd.y = wt.y - wb.y;
      wd.z = wt.z - wb.z; wd.w = wt.w - wb.w;
      *reinterpret_cast<float4*>(&Wd[k][h4]) = wd;
    }
    __syncthreads();
#pragma unroll
    for (int k = 0; k < BK; ++k) {
      float a[8];
#pragma unroll
      for (int i = 0; i < 8; ++i) a[i] = As[ty * 8 + i][k];
      const float4 wd4 = *reinterpret_cast<const float4*>(&Wd[k][tx * 4]);
      const float4 wb4 = *reinterpret_cast<const float4*>(&Wb[k][tx * 4]);
      const float wdv[4] = {wd4.x, wd4.y, wd4.z, wd4.w};
      const float wbv[4] = {wb4.x, wb4.y, wb4.z, wb4.w};
#pragma unroll
      for (int i = 0; i < 8; ++i)
#pragma unroll
        for (int j = 0; j < 4; ++j) {
          accU[i][j] = fmaf(a[i], wdv[j], accU[i][j]);
          accV[i][j] = fmaf(a[i], wbv[j], accV[i][j]);
        }
    }
  }
  // Epilogue: slice 0 adds the bias exactly once; atomicAdd into zeroed U/V.
  const int cbase = h0 + tx * 4;
  float bb[4] = {0.f, 0.f, 0.f, 0.f};
  if (blockIdx.y == 0) {
#pragma unroll
    for (int j = 0; j < 4; ++j) bb[j] = bias[cbase + j];
  }
#pragma unroll
  for (int i = 0; i < 8; ++i) {
    const int row = ty * 8 + i;
#pragma unroll
    for (int j = 0; j < 4; ++j) {
      atomicAdd(&U[row * HDIM + cbase + j], accU[i][j] + bb[j]);
      atomicAdd(&V[row * HDIM + cbase + j], accV[i][j]);
    }
  }
}

// ---------------------------------------------------------------------------
// K2/K4: per-d pair GEMM + fused masked max + bias + relu.  (unchanged)
// ---------------------------------------------------------------------------
__global__ __launch_bounds__(256) void pair_gemm_max_kernel(
    const float* __restrict__ U, const float* __restrict__ V,
    const float* __restrict__ W2, const float* __restrict__ b2,
    const unsigned int* __restrict__ mask, float* __restrict__ out) {
  __shared__ float As[16][128];
  __shared__ float Bs[16][128];
  const int t = threadIdx.x;
  const int tx = t & 15, ty = t >> 4;
  const int d = blockIdx.y;
  const int c0 = blockIdx.x * 128;

  float acc[8][8];
#pragma unroll
  for (int i = 0; i < 8; ++i)
#pragma unroll
    for (int j = 0; j < 8; ++j) acc[i][j] = 0.f;

  for (int kb = 0; kb < HDIM / 16; ++kb) {
    __syncthreads();
#pragma unroll
    for (int r = 0; r < 2; ++r) {
      const int q = t + r * 256;
      const int s = q >> 2;
      const int k4 = (q & 3) * 4;
      const float4 v4 = *reinterpret_cast<const float4*>(&V[s * HDIM + kb * 16 + k4]);
      const float4 u4 = *reinterpret_cast<const float4*>(&U[d * HDIM + kb * 16 + k4]);
      As[k4 + 0][s] = fmaxf(u4.x + v4.x, 0.f);
      As[k4 + 1][s] = fmaxf(u4.y + v4.y, 0.f);
      As[k4 + 2][s] = fmaxf(u4.z + v4.z, 0.f);
      As[k4 + 3][s] = fmaxf(u4.w + v4.w, 0.f);
    }
#pragma unroll
    for (int r = 0; r < 2; ++r) {
      const int q = t + r * 256;
      const int k = q >> 5;
      const int c4 = (q & 31) * 4;
      *reinterpret_cast<float4*>(&Bs[k][c4]) =
          *reinterpret_cast<const float4*>(&W2[(kb * 16 + k) * HDIM + c0 + c4]);
    }
    __syncthreads();
#pragma unroll
    for (int k = 0; k < 16; ++k) {
      const float4 a0 = *reinterpret_cast<const float4*>(&As[k][ty * 8]);
      const float4 a1 = *reinterpret_cast<const float4*>(&As[k][ty * 8 + 4]);
      const float4 b0 = *reinterpret_cast<const float4*>(&Bs[k][tx * 8]);
      const float4 b1 = *reinterpret_cast<const float4*>(&Bs[k][tx * 8 + 4]);
      const float av[8] = {a0.x, a0.y, a0.z, a0.w, a1.x, a1.y, a1.z, a1.w};
      const float bv[8] = {b0.x, b0.y, b0.z, b0.w, b1.x, b1.y, b1.z, b1.w};
#pragma unroll
      for (int i = 0; i < 8; ++i)
#pragma unroll
        for (int j = 0; j < 8; ++j) acc[i][j] = fmaf(av[i], bv[j], acc[i][j]);
    }
  }
  __syncthreads();

  const unsigned int w = mask[d * 4 + (ty >> 2)];
  float cm[8];
#pragma unroll
  for (int j = 0; j < 8; ++j) cm[j] = -FLT_MAX;
#pragma unroll
  for (int i = 0; i < 8; ++i) {
    if ((w >> ((ty & 3) * 8 + i)) & 1u) {
#pragma unroll
      for (int j = 0; j < 8; ++j) cm[j] = fmaxf(cm[j], acc[i][j]);
    }
  }
  float(*red)[128] = As;
#pragma unroll
  for (int j = 0; j < 8; ++j) red[ty][tx * 8 + j] = cm[j];
  __syncthreads();
  if (t < 128) {
    float m = -FLT_MAX;
#pragma unroll
    for (int r2 = 0; r2 < 16; ++r2) m = fmaxf(m, red[r2][t]);
    const int gc = c0 + t;
    out[d * HDIM + gc] = fmaxf(m + b2[gc], 0.f);
  }
}

// ---------------------------------------------------------------------------
// K5 v2: z0[j] += sum_i v[i] * lin_W[i, j]  (512 blocks of 128 rows, float4)
// ---------------------------------------------------------------------------
__global__ __launch_bounds__(256) void head_gemv_kernel(
    const float* __restrict__ v, const float* __restrict__ W,
    float* __restrict__ z0) {
  __shared__ float vs[128];
  __shared__ float4 red[128];
  const int t = threadIdx.x;
  const int bi = blockIdx.x;
  if (t < 128) vs[t] = v[bi * 128 + t];
  __syncthreads();
  const int c4 = (t & 127) * 4;
  const int half = t >> 7;  // 0 or 1 -> rows [half*64, half*64+64)
  const float* Wp = W + (size_t)bi * 128 * 512;
  float4 acc = make_float4(0.f, 0.f, 0.f, 0.f);
#pragma unroll 8
  for (int i = 0; i < 64; ++i) {
    const int row = half * 64 + i;
    const float4 w4 = *reinterpret_cast<const float4*>(&Wp[(size_t)row * 512 + c4]);
    const float x = vs[row];
    acc.x = fmaf(x, w4.x, acc.x);
    acc.y = fmaf(x, w4.y, acc.y);
    acc.z = fmaf(x, w4.z, acc.z);
    acc.w = fmaf(x, w4.w, acc.w);
  }
  if (half == 1) red[t & 127] = acc;
  __syncthreads();
  if (half == 0) {
    const float4 o = red[t];
    atomicAdd(&z0[c4 + 0], acc.x + o.x);
    atomicAdd(&z0[c4 + 1], acc.y + o.y);
    atomicAdd(&z0[c4 + 2], acc.z + o.z);
    atomicAdd(&z0[c4 + 3], acc.w + o.w);
  }
}

// ---------------------------------------------------------------------------
// K6a: z1[c] += relu(z0+lin_b)[k-slice] @ lin1W[k-slice, c]  (8 k-slices)
// ---------------------------------------------------------------------------
__global__ __launch_bounds__(256) void z1_kernel(
    const float* __restrict__ z0, const float* __restrict__ lin_b,
    const float* __restrict__ lin1W, float* __restrict__ z1) {
  __shared__ float zr[64];
  const int t = threadIdx.x;
  const int k0 = blockIdx.x * 64;
  if (t < 64) zr[t] = fmaxf(z0[k0 + t] + lin_b[k0 + t], 0.f);
  __syncthreads();
  float acc = 0.f;
#pragma unroll 8
  for (int i = 0; i < 64; ++i)
    acc = fmaf(zr[i], lin1W[(size_t)(k0 + i) * 256 + t], acc);
  atomicAdd(&z1[t], acc);
}

// ---------------------------------------------------------------------------
// K6b: z2[c] += relu(z1+lin1_b)[k-slice] @ outW[k-slice, c]  (4 k-slices)
// ---------------------------------------------------------------------------
__global__ __launch_bounds__(128) void z2_kernel(
    const float* __restrict__ z1, const float* __restrict__ lin1b,
    const float* __restrict__ outW, float* __restrict__ z2) {
  __shared__ float zr[64];
  const int t = threadIdx.x;
  const int k0 = blockIdx.x * 64;
  if (t < 64) zr[t] = fmaxf(z1[k0 + t] + lin1b[k0 + t], 0.f);
  __syncthreads();
  float acc = 0.f;
#pragma unroll 8
  for (int i = 0; i < 64; ++i)
    acc = fmaf(zr[i], outW[(size_t)(k0 + i) * 128 + t], acc);
  atomicAdd(&z2[t], acc);
}

// ---------------------------------------------------------------------------
// K6c: out = softmax(relu(z2 + out_b)), 1 block x 128 threads
// ---------------------------------------------------------------------------
__global__ __launch_bounds__(128) void softmax_kernel(
    const float* __restrict__ z2, const float* __restrict__ outb,
    float* __restrict__ out) {
  __shared__ float zs[128];
  __shared__ float r[128];
  const int t = threadIdx.x;
  const float z = fmaxf(z2[t] + outb[t], 0.f);
  zs[t] = z;
  r[t] = z;
  __syncthreads();
  for (int off = 64; off > 0; off >>= 1) {
    if (t < off) r[t] = fmaxf(r[t], r[t + off]);
    __syncthreads();
  }
  const float mx = r[0];
  __syncthreads();
  const float e = expf(zs[t] - mx);
  r[t] = e;
  __syncthreads();
  for (int off = 64; off > 0; off >>= 1) {
    if (t < off) r[t] += r[t + off];
    __syncthreads();
  }
  out[t] = e / r[0];
}

// ---------------------------------------------------------------------------
extern "C" void kernel_launch(void* const* d_in, const int* in_sizes, int n_in,
                              void* d_out, int out_size, void* d_ws,
                              size_t ws_size, hipStream_t stream) {
  const float* x      = (const float*)d_in[0];
  const int*   ei     = (const int*)d_in[1];
  const float* c1_W1  = (const float*)d_in[2];
  const float* c1_b1  = (const float*)d_in[3];
  const float* c1_W2  = (const float*)d_in[4];
  const float* c1_b2  = (const float*)d_in[5];
  const float* c2_W1  = (const float*)d_in[6];
  const float* c2_b1  = (const float*)d_in[7];
  const float* c2_W2  = (const float*)d_in[8];
  const float* c2_b2  = (const float*)d_in[9];
  const float* lin_W  = (const float*)d_in[10];
  const float* lin_b  = (const float*)d_in[11];
  const float* lin1_W = (const float*)d_in[12];
  const float* lin1_b = (const float*)d_in[13];
  const float* out_W  = (const float*)d_in[14];
  const float* out_b  = (const float*)d_in[15];
  float* out = (float*)d_out;

  char* wsb = (char*)d_ws;
  unsigned int* mask = (unsigned int*)wsb;          // 512 u32 = 2048 B
  float* zero_base = (float*)(wsb + 2048);
  float* U1 = zero_base;                            // 128x512
  float* V1 = U1 + 65536;
  float* U2 = V1 + 65536;
  float* V2 = U2 + 65536;
  float* z0 = V2 + 65536;                           // 512
  float* z1 = z0 + 512;                             // 256
  float* z2 = z1 + 256;                             // 128
  float* h1 = z2 + 128;                             // 128x512 (no zeroing)
  float* h2 = h1 + 65536;

  hipMemsetAsync(mask, 0, 2048, stream);
  hipMemsetAsync(zero_base, 0, (4 * 65536 + 512 + 256 + 128) * sizeof(float),
                 stream);

  build_mask_kernel<<<256, 256, 0, stream>>>(ei, mask);
  uv_gemm2_kernel<256, 4><<<dim3(8, 4), 256, 0, stream>>>(x, c1_W1, c1_b1, U1, V1);
  pair_gemm_max_kernel<<<dim3(4, 128), 256, 0, stream>>>(U1, V1, c1_W2, c1_b2, mask, h1);
  uv_gemm2_kernel<512, 4><<<dim3(8, 4), 256, 0, stream>>>(h1, c2_W1, c2_b1, U2, V2);
  pair_gemm_max_kernel<<<dim3(4, 128), 256, 0, stream>>>(U2, V2, c2_W2, c2_b2, mask, h2);
  head_gemv_kernel<<<512, 256, 0, stream>>>(h2, lin_W, z0);
  z1_kernel<<<8, 256, 0, stream>>>(z0, lin_b, lin1_W, z1);
  z2_kernel<<<4, 128, 0, stream>>>(z1, lin1_b, out_W, z2);
  softmax_kernel<<<1, 128, 0, stream>>>(z2, out_b, out);
}

// Round 3
// 384.871 us; speedup vs baseline: 2.1557x; 1.4822x over previous
//
#include <hip/hip_runtime.h>
#include <cfloat>
#include <cmath>
#include <cstdint>

#define N_NODES 128
#define F_IN    256
#define HDIM    512
#define NEDGE   524288

typedef _Float16 half8 __attribute__((ext_vector_type(8)));
typedef _Float16 half4 __attribute__((ext_vector_type(4)));
typedef float f32x4 __attribute__((ext_vector_type(4)));

// ---------------------------------------------------------------------------
// K0: adjacency bitmask  mask[d] = bitset over s of "edge (s -> d) exists"
// ---------------------------------------------------------------------------
__global__ __launch_bounds__(256) void build_mask_kernel(
    const int* __restrict__ ei, unsigned int* __restrict__ mask) {
  __shared__ unsigned int lm[N_NODES * 4];
  const int t = threadIdx.x;
  for (int i = t; i < N_NODES * 4; i += 256) lm[i] = 0u;
  __syncthreads();
  const int base = blockIdx.x * 2048;
#pragma unroll
  for (int r = 0; r < 8; ++r) {
    const int e = base + r * 256 + t;
    const int s = ei[e];          // src  (x_j)
    const int d = ei[NEDGE + e];  // dst  (x_i, segment target)
    atomicOr(&lm[d * 4 + (s >> 5)], 1u << (s & 31));
  }
  __syncthreads();
  for (int i = t; i < N_NODES * 4; i += 256) {
    const unsigned int v = lm[i];
    if (v) atomicOr(&mask[i], v);
  }
}

// ---------------------------------------------------------------------------
// K-pre: convert W2 (f32 [k][n] 512x512) -> f16 transposed [n][k] for both
// layers. Grid (8 k-tiles, 8 n-tiles, 2 layers), 64x64 tiles via LDS.
// ---------------------------------------------------------------------------
__global__ __launch_bounds__(256) void cvt_w2_kernel(
    const float* __restrict__ W2a, const float* __restrict__ W2b,
    _Float16* __restrict__ Ta, _Float16* __restrict__ Tb) {
  const float* W = blockIdx.z ? W2b : W2a;
  _Float16* T = blockIdx.z ? Tb : Ta;
  __shared__ _Float16 tile[64][72];
  const int t = threadIdx.x;
  const int kb = blockIdx.x * 64;
  const int nb = blockIdx.y * 64;
#pragma unroll
  for (int i = 0; i < 4; ++i) {
    const int slot = t + i * 256;      // 1024 = 64 kk x 16 nq
    const int kk = slot >> 4;
    const int nq = (slot & 15) * 4;
    const float4 w4 =
        *reinterpret_cast<const float4*>(&W[(size_t)(kb + kk) * HDIM + nb + nq]);
    tile[nq + 0][kk] = (_Float16)w4.x;
    tile[nq + 1][kk] = (_Float16)w4.y;
    tile[nq + 2][kk] = (_Float16)w4.z;
    tile[nq + 3][kk] = (_Float16)w4.w;
  }
  __syncthreads();
#pragma unroll
  for (int i = 0; i < 2; ++i) {
    const int slot = t + i * 256;      // 512 = 64 n x 8 ko
    const int n = slot >> 3;
    const int ko = (slot & 7) * 8;
    *reinterpret_cast<half8*>(&T[(size_t)(nb + n) * HDIM + kb + ko]) =
        *reinterpret_cast<const half8*>(&tile[n][ko]);
  }
}

// ---------------------------------------------------------------------------
// K1/K3 v3: U[d,h] = A[d]@(Wtop-Wbot)[.,h]+b[h], V[d,h] = A[d]@Wbot[.,h]
// Grid (16 h-tiles of 32, 8 K-slices) = 128 blocks. Block: 128d x 32h.
// Thread: tx=t&7 (4 h), ty=t>>3 (4 d) -> 4x4x2 accs. atomicAdd into zeroed U/V.
// ---------------------------------------------------------------------------
template <int KK>
__global__ __launch_bounds__(256) void uv_gemm3_kernel(
    const float* __restrict__ A, const float* __restrict__ W,
    const float* __restrict__ bias, float* __restrict__ U,
    float* __restrict__ V) {
  constexpr int S = 8;
  constexpr int KS = KK / S;
  constexpr int BK = 32;
  __shared__ float As[128][BK + 1];
  __shared__ float Wd[BK][36];
  __shared__ float Wb[BK][36];
  const int t = threadIdx.x;
  const int tx = t & 7;
  const int ty = t >> 3;
  const int h0 = blockIdx.x * 32;
  const int ks0 = blockIdx.y * KS;

  float accU[4][4], accV[4][4];
#pragma unroll
  for (int i = 0; i < 4; ++i)
#pragma unroll
    for (int j = 0; j < 4; ++j) { accU[i][j] = 0.f; accV[i][j] = 0.f; }

  for (int ch = 0; ch < KS / BK; ++ch) {
    const int k0 = ks0 + ch * BK;
    __syncthreads();
    // A chunk: 128 x 32 f32 (1024 float4, 4/thread)
#pragma unroll
    for (int i = 0; i < 4; ++i) {
      const int slot = t + i * 256;
      const int dd = slot >> 3, kw = (slot & 7) * 4;
      const float4 a4 =
          *reinterpret_cast<const float4*>(&A[dd * KK + k0 + kw]);
      As[dd][kw + 0] = a4.x;
      As[dd][kw + 1] = a4.y;
      As[dd][kw + 2] = a4.z;
      As[dd][kw + 3] = a4.w;
    }
    // W chunk: 32k x 32h, top & bottom (1 float4 pair per thread)
    {
      const int k = t >> 3, hq = (t & 7) * 4;
      const float4 wt = *reinterpret_cast<const float4*>(
          &W[(size_t)(k0 + k) * HDIM + h0 + hq]);
      const float4 wb = *reinterpret_cast<const float4*>(
          &W[(size_t)(KK + k0 + k) * HDIM + h0 + hq]);
      *reinterpret_cast<float4*>(&Wb[k][hq]) = wb;
      float4 wd;
      wd.x = wt.x - wb.x; wd.y = wt.y - wb.y;
      wd.z = wt.z - wb.z; wd.w = wt.w - wb.w;
      *reinterpret_cast<float4*>(&Wd[k][hq]) = wd;
    }
    __syncthreads();
#pragma unroll
    for (int k = 0; k < BK; ++k) {
      float a[4];
#pragma unroll
      for (int i = 0; i < 4; ++i) a[i] = As[ty * 4 + i][k];
      const float4 wd4 = *reinterpret_cast<const float4*>(&Wd[k][tx * 4]);
      const float4 wb4 = *reinterpret_cast<const float4*>(&Wb[k][tx * 4]);
      const float wdv[4] = {wd4.x, wd4.y, wd4.z, wd4.w};
      const float wbv[4] = {wb4.x, wb4.y, wb4.z, wb4.w};
#pragma unroll
      for (int i = 0; i < 4; ++i)
#pragma unroll
        for (int j = 0; j < 4; ++j) {
          accU[i][j] = fmaf(a[i], wdv[j], accU[i][j]);
          accV[i][j] = fmaf(a[i], wbv[j], accV[i][j]);
        }
    }
  }
  const int cbase = h0 + tx * 4;
  float bb[4] = {0.f, 0.f, 0.f, 0.f};
  if (blockIdx.y == 0) {
#pragma unroll
    for (int j = 0; j < 4; ++j) bb[j] = bias[cbase + j];
  }
#pragma unroll
  for (int i = 0; i < 4; ++i) {
    const int row = ty * 4 + i;
#pragma unroll
    for (int j = 0; j < 4; ++j) {
      atomicAdd(&U[row * HDIM + cbase + j], accU[i][j] + bb[j]);
      atomicAdd(&V[row * HDIM + cbase + j], accV[i][j]);
    }
  }
}

// ---------------------------------------------------------------------------
// K2/K4 v2: MFMA fp16 pair GEMM + fused masked max + bias + relu.
// Block = (d, 256-col tile); 4 waves, each wave: 64 n-cols x 128 s-rows.
// A[s,k] = (f16)relu(U[d,k]+V[s,k]) staged per 64-k chunk; B = W2t f16 [n][k].
// MFMA 16x16x32_f16: A[m=lane&15][k=quad*8+j]; B[n=lane&15][k=quad*8+j];
// C/D col=lane&15, row=quad*4+reg (verified layouts).
// ---------------------------------------------------------------------------
#define PBK 64
__global__ __launch_bounds__(256, 1) void pair_mfma_kernel(
    const float* __restrict__ U, const float* __restrict__ V,
    const _Float16* __restrict__ W2t, const float* __restrict__ b2,
    const unsigned int* __restrict__ mask, float* __restrict__ out) {
  __shared__ _Float16 As[128][PBK + 8];   // 18.4 KB
  __shared__ _Float16 Bs[256][PBK + 8];   // 36.9 KB
  __shared__ float Ur[HDIM];              // 2 KB
  __shared__ float red[4][256];           // 4 KB
  const int t = threadIdx.x;
  const int d = blockIdx.y;
  const int c0 = blockIdx.x * 256;
  const int lane = t & 63;
  const int wid = t >> 6;
  const int l15 = lane & 15;
  const int quad = lane >> 4;

  for (int i = t; i < HDIM; i += 256) Ur[i] = U[d * HDIM + i];
  const unsigned int mw0 = mask[d * 4 + 0];
  const unsigned int mw1 = mask[d * 4 + 1];
  const unsigned int mw2 = mask[d * 4 + 2];
  const unsigned int mw3 = mask[d * 4 + 3];

  f32x4 acc[8][4];
#pragma unroll
  for (int mt = 0; mt < 8; ++mt)
#pragma unroll
    for (int nt = 0; nt < 4; ++nt) acc[mt][nt] = (f32x4)(0.f);

  for (int ch = 0; ch < HDIM / PBK; ++ch) {
    const int k0 = ch * PBK;
    __syncthreads();
    // Stage A: relu(U+V) -> f16, 128 s x 64 k (2048 float4 src, 8/thread)
#pragma unroll
    for (int i = 0; i < 8; ++i) {
      const int slot = t + i * 256;
      const int s = slot >> 4;
      const int kq = (slot & 15) * 4;
      const float4 v4 =
          *reinterpret_cast<const float4*>(&V[s * HDIM + k0 + kq]);
      const float4 u4 = *reinterpret_cast<const float4*>(&Ur[k0 + kq]);
      half4 h;
      h.x = (_Float16)fmaxf(u4.x + v4.x, 0.f);
      h.y = (_Float16)fmaxf(u4.y + v4.y, 0.f);
      h.z = (_Float16)fmaxf(u4.z + v4.z, 0.f);
      h.w = (_Float16)fmaxf(u4.w + v4.w, 0.f);
      *reinterpret_cast<half4*>(&As[s][kq]) = h;
    }
    // Stage B: W2t rows [c0..c0+256), 64 k f16 (2048 half8, 8/thread)
#pragma unroll
    for (int i = 0; i < 8; ++i) {
      const int slot = t + i * 256;
      const int n = slot >> 3;
      const int ko = (slot & 7) * 8;
      *reinterpret_cast<half8*>(&Bs[n][ko]) = *reinterpret_cast<const half8*>(
          &W2t[(size_t)(c0 + n) * HDIM + k0 + ko]);
    }
    __syncthreads();
#pragma unroll
    for (int ks = 0; ks < PBK / 32; ++ks) {
      half8 bf[4];
#pragma unroll
      for (int nt = 0; nt < 4; ++nt)
        bf[nt] = *reinterpret_cast<const half8*>(
            &Bs[wid * 64 + nt * 16 + l15][ks * 32 + quad * 8]);
#pragma unroll
      for (int mt = 0; mt < 8; ++mt) {
        const half8 af = *reinterpret_cast<const half8*>(
            &As[mt * 16 + l15][ks * 32 + quad * 8]);
#pragma unroll
        for (int nt = 0; nt < 4; ++nt)
          acc[mt][nt] = __builtin_amdgcn_mfma_f32_16x16x32_f16(
              af, bf[nt], acc[mt][nt], 0, 0, 0);
      }
    }
  }
  __syncthreads();
  // Epilogue: masked max over s (m-dim), then +b2, relu.
  const unsigned int mwv[4] = {mw0, mw1, mw2, mw3};
#pragma unroll
  for (int nt = 0; nt < 4; ++nt) {
    float pm = -FLT_MAX;
#pragma unroll
    for (int mt = 0; mt < 8; ++mt) {
      const int sbase = mt * 16 + quad * 4;
      const unsigned int w = mwv[sbase >> 5] >> (sbase & 31);
#pragma unroll
      for (int r = 0; r < 4; ++r)
        if ((w >> r) & 1u) pm = fmaxf(pm, acc[mt][nt][r]);
    }
    red[quad][wid * 64 + nt * 16 + l15] = pm;
  }
  __syncthreads();
  const float m = fmaxf(fmaxf(red[0][t], red[1][t]),
                        fmaxf(red[2][t], red[3][t]));
  out[d * HDIM + c0 + t] = fmaxf(m + b2[c0 + t], 0.f);
}

// ---------------------------------------------------------------------------
// K5: z0[j] += sum_i v[i] * lin_W[i, j]  (512 blocks of 128 rows, float4)
// ---------------------------------------------------------------------------
__global__ __launch_bounds__(256) void head_gemv_kernel(
    const float* __restrict__ v, const float* __restrict__ W,
    float* __restrict__ z0) {
  __shared__ float vs[128];
  __shared__ float4 red[128];
  const int t = threadIdx.x;
  const int bi = blockIdx.x;
  if (t < 128) vs[t] = v[bi * 128 + t];
  __syncthreads();
  const int c4 = (t & 127) * 4;
  const int half = t >> 7;
  const float* Wp = W + (size_t)bi * 128 * 512;
  float4 acc = make_float4(0.f, 0.f, 0.f, 0.f);
#pragma unroll 8
  for (int i = 0; i < 64; ++i) {
    const int row = half * 64 + i;
    const float4 w4 =
        *reinterpret_cast<const float4*>(&Wp[(size_t)row * 512 + c4]);
    const float x = vs[row];
    acc.x = fmaf(x, w4.x, acc.x);
    acc.y = fmaf(x, w4.y, acc.y);
    acc.z = fmaf(x, w4.z, acc.z);
    acc.w = fmaf(x, w4.w, acc.w);
  }
  if (half == 1) red[t & 127] = acc;
  __syncthreads();
  if (half == 0) {
    const float4 o = red[t];
    atomicAdd(&z0[c4 + 0], acc.x + o.x);
    atomicAdd(&z0[c4 + 1], acc.y + o.y);
    atomicAdd(&z0[c4 + 2], acc.z + o.z);
    atomicAdd(&z0[c4 + 3], acc.w + o.w);
  }
}

// ---------------------------------------------------------------------------
__global__ __launch_bounds__(256) void z1_kernel(
    const float* __restrict__ z0, const float* __restrict__ lin_b,
    const float* __restrict__ lin1W, float* __restrict__ z1) {
  __shared__ float zr[64];
  const int t = threadIdx.x;
  const int k0 = blockIdx.x * 64;
  if (t < 64) zr[t] = fmaxf(z0[k0 + t] + lin_b[k0 + t], 0.f);
  __syncthreads();
  float acc = 0.f;
#pragma unroll 8
  for (int i = 0; i < 64; ++i)
    acc = fmaf(zr[i], lin1W[(size_t)(k0 + i) * 256 + t], acc);
  atomicAdd(&z1[t], acc);
}

__global__ __launch_bounds__(128) void z2_kernel(
    const float* __restrict__ z1, const float* __restrict__ lin1b,
    const float* __restrict__ outW, float* __restrict__ z2) {
  __shared__ float zr[64];
  const int t = threadIdx.x;
  const int k0 = blockIdx.x * 64;
  if (t < 64) zr[t] = fmaxf(z1[k0 + t] + lin1b[k0 + t], 0.f);
  __syncthreads();
  float acc = 0.f;
#pragma unroll 8
  for (int i = 0; i < 64; ++i)
    acc = fmaf(zr[i], outW[(size_t)(k0 + i) * 128 + t], acc);
  atomicAdd(&z2[t], acc);
}

__global__ __launch_bounds__(128) void softmax_kernel(
    const float* __restrict__ z2, const float* __restrict__ outb,
    float* __restrict__ out) {
  __shared__ float zs[128];
  __shared__ float r[128];
  const int t = threadIdx.x;
  const float z = fmaxf(z2[t] + outb[t], 0.f);
  zs[t] = z;
  r[t] = z;
  __syncthreads();
  for (int off = 64; off > 0; off >>= 1) {
    if (t < off) r[t] = fmaxf(r[t], r[t + off]);
    __syncthreads();
  }
  const float mx = r[0];
  __syncthreads();
  const float e = expf(zs[t] - mx);
  r[t] = e;
  __syncthreads();
  for (int off = 64; off > 0; off >>= 1) {
    if (t < off) r[t] += r[t + off];
    __syncthreads();
  }
  out[t] = e / r[0];
}

// ---------------------------------------------------------------------------
extern "C" void kernel_launch(void* const* d_in, const int* in_sizes, int n_in,
                              void* d_out, int out_size, void* d_ws,
                              size_t ws_size, hipStream_t stream) {
  const float* x      = (const float*)d_in[0];
  const int*   ei     = (const int*)d_in[1];
  const float* c1_W1  = (const float*)d_in[2];
  const float* c1_b1  = (const float*)d_in[3];
  const float* c1_W2  = (const float*)d_in[4];
  const float* c1_b2  = (const float*)d_in[5];
  const float* c2_W1  = (const float*)d_in[6];
  const float* c2_b1  = (const float*)d_in[7];
  const float* c2_W2  = (const float*)d_in[8];
  const float* c2_b2  = (const float*)d_in[9];
  const float* lin_W  = (const float*)d_in[10];
  const float* lin_b  = (const float*)d_in[11];
  const float* lin1_W = (const float*)d_in[12];
  const float* lin1_b = (const float*)d_in[13];
  const float* out_W  = (const float*)d_in[14];
  const float* out_b  = (const float*)d_in[15];
  float* out = (float*)d_out;

  char* wsb = (char*)d_ws;
  unsigned int* mask = (unsigned int*)wsb;          // 2048 B
  float* zero_base = (float*)(wsb + 2048);
  float* U1 = zero_base;                            // 128x512 f32 each
  float* V1 = U1 + 65536;
  float* U2 = V1 + 65536;
  float* V2 = U2 + 65536;
  float* z0 = V2 + 65536;                           // 512
  float* z1 = z0 + 512;                             // 256
  float* z2 = z1 + 256;                             // 128
  float* h1 = z2 + 128;                             // 128x512 f32 (no zeroing)
  float* h2 = h1 + 65536;
  _Float16* W2t1 = (_Float16*)(h2 + 65536);         // 512x512 f16 each
  _Float16* W2t2 = W2t1 + 262144;

  hipMemsetAsync(mask, 0, 2048, stream);
  hipMemsetAsync(zero_base, 0, (4 * 65536 + 512 + 256 + 128) * sizeof(float),
                 stream);

  cvt_w2_kernel<<<dim3(8, 8, 2), 256, 0, stream>>>(c1_W2, c2_W2, W2t1, W2t2);
  build_mask_kernel<<<256, 256, 0, stream>>>(ei, mask);
  uv_gemm3_kernel<256><<<dim3(16, 8), 256, 0, stream>>>(x, c1_W1, c1_b1, U1, V1);
  pair_mfma_kernel<<<dim3(2, 128), 256, 0, stream>>>(U1, V1, W2t1, c1_b2, mask, h1);
  uv_gemm3_kernel<512><<<dim3(16, 8), 256, 0, stream>>>(h1, c2_W1, c2_b1, U2, V2);
  pair_mfma_kernel<<<dim3(2, 128), 256, 0, stream>>>(U2, V2, W2t2, c2_b2, mask, h2);
  head_gemv_kernel<<<512, 256, 0, stream>>>(h2, lin_W, z0);
  z1_kernel<<<8, 256, 0, stream>>>(z0, lin_b, lin1_W, z1);
  z2_kernel<<<4, 128, 0, stream>>>(z1, lin1_b, out_W, z2);
  softmax_kernel<<<1, 128, 0, stream>>>(z2, out_b, out);
}